// Round 5
// baseline (498.078 us; speedup 1.0000x reference)
//
#include <hip/hip_runtime.h>

#define B_ 8
#define T_ 4096
#define D_ 1024
#define H_ 8
#define BW_ 128
#define NC_ 32           // scan chunks (128 rows each)
#define CT_ 128
#define EPS7 1e-7f
#define EPS5 1e-5f
#define LOG1MEPS -1.0000186e-05f   // log(1 - 1e-5)
#define OMSCALE 256.0f
#define INVOMS 0.00390625f         // 1/256

typedef _Float16 f16x8 __attribute__((ext_vector_type(8)));
typedef _Float16 f16x4 __attribute__((ext_vector_type(4)));
typedef _Float16 f16x2 __attribute__((ext_vector_type(2)));
typedef float f32x4 __attribute__((ext_vector_type(4)));

// ---------------------------------------------------------------------------
// K1: block (b, head, 128-row tile). Gate matmuls on MFMA f16 (16x16x32).
// Weight load = round-2's proven gather (col permuted). Column permutation:
// MFMA logical col l15 -> actual col wave*32 + 2*l15 + jt, so each thread's
// two output columns are ADJACENT. Output interleaved AU[t][d] = (a_enc, nx)
// f16 pairs written as f16x4 (8 B/lane coalesced; was 128 scattered 2B
// stores). a_enc = (1-a)*256 (raw a would round to 1.0 in f16).
// ---------------------------------------------------------------------------
__global__ __launch_bounds__(256) void k1_gates(
    const float* __restrict__ x, const float* __restrict__ a_param,
    const float* __restrict__ w_in, const float* __restrict__ b_in,
    const float* __restrict__ w_a, const float* __restrict__ b_a,
    f16x2* __restrict__ AU, float* __restrict__ CS)
{
  const int bid  = blockIdx.x;
  const int kc   = bid & (NC_ - 1);
  const int h    = (bid >> 5) & (H_ - 1);
  const int b    = bid >> 8;
  const int tid  = threadIdx.x;
  const int wave = tid >> 6;
  const int lane = tid & 63;
  const int quad = lane >> 4;
  const int l15  = lane & 15;

  __shared__ _Float16 xs[128 * 136];   // 128 rows x 128 K f16, pad 8/row

  const float* xg = x + (size_t)(b * T_ + kc * CT_) * D_ + h * BW_;
  const int jcp = wave * 32 + 2 * l15;   // even pair-column within head

  // --- B fragments (weights) from global, round-2 gather, permuted col ---
  // lane holds w[k = kstep*32 + quad*8 + i][col = jcp + jt]
  f16x8 bf[2][2][4];   // [gate][jtile][kstep]
  #pragma unroll
  for (int g = 0; g < 2; ++g) {
    const float* wptr = (g ? w_a : w_in) + h * BW_ * BW_;
    #pragma unroll
    for (int jt = 0; jt < 2; ++jt) {
      #pragma unroll
      for (int k = 0; k < 4; ++k) {
        const float* wp = wptr + (k * 32 + quad * 8) * BW_ + jcp + jt;
        f16x8 f;
        #pragma unroll
        for (int i = 0; i < 8; ++i) f[i] = (_Float16)wp[i * BW_];
        bf[g][jt][k] = f;
      }
    }
  }
  // per-lane j constants (actual columns jcp+jt)
  float bI[2], bA[2], cdec[2];
  #pragma unroll
  for (int jt = 0; jt < 2; ++jt) {
    const int j = h * BW_ + jcp + jt;
    bI[jt] = b_in[j];
    bA[jt] = b_a[j];
    const float ap = a_param[j];
    cdec[jt] = ((ap > 20.f) ? ap : log1pf(__expf(ap))) + 0.001f;
  }

  // --- stage x -> LDS f16; per half-wave: one row, 512 B contiguous ---
  {
    const int rr = tid >> 5;          // 0..7
    const int cc = (tid & 31) * 4;    // 0..124
    #pragma unroll
    for (int i = 0; i < 16; ++i) {
      const int row = i * 8 + rr;
      const float4 v = *(const float4*)(xg + row * D_ + cc);
      f16x4 hv = { (_Float16)v.x, (_Float16)v.y, (_Float16)v.z, (_Float16)v.w };
      *(f16x4*)(xs + row * 136 + cc) = hv;
    }
  }
  __syncthreads();

  // --- MFMA main loop: 8 m-tiles x 4 k-steps x 2 gates x 2 j-tiles ---
  f32x4 acc[2][2][8];
  #pragma unroll
  for (int g = 0; g < 2; ++g)
    #pragma unroll
    for (int jt = 0; jt < 2; ++jt)
      #pragma unroll
      for (int m = 0; m < 8; ++m)
        acc[g][jt][m] = (f32x4){0.f, 0.f, 0.f, 0.f};

  #pragma unroll
  for (int m = 0; m < 8; ++m) {
    f16x8 af[4];
    #pragma unroll
    for (int k = 0; k < 4; ++k)
      af[k] = *(const f16x8*)(xs + (m * 16 + l15) * 136 + k * 32 + quad * 8);
    #pragma unroll
    for (int k = 0; k < 4; ++k)
      #pragma unroll
      for (int g = 0; g < 2; ++g)
        #pragma unroll
        for (int jt = 0; jt < 2; ++jt)
          acc[g][jt][m] = __builtin_amdgcn_mfma_f32_16x16x32_f16(
              af[k], bf[g][jt][k], acc[g][jt][m], 0, 0, 0);
  }

  // --- epilogue: D layout col(logical)=l15, row = m*16 + quad*4 + reg ---
  float sla[2] = {0.f, 0.f};
  const size_t obase = (size_t)(b * T_ + kc * CT_) * D_ + h * BW_ + jcp;
  #pragma unroll
  for (int m = 0; m < 8; ++m) {
    #pragma unroll
    for (int r = 0; r < 4; ++r) {
      const int row = m * 16 + quad * 4 + r;
      const f16x2 xv = *(const f16x2*)(xs + row * 136 + jcp);
      float aenc[2], nxv[2];
      #pragma unroll
      for (int jt = 0; jt < 2; ++jt) {
        const float yi = acc[0][jt][m][r] + bI[jt];
        const float ya = acc[1][jt][m][r] + bA[jt];
        const float gx = __builtin_amdgcn_rcpf(1.f + __expf(-yi));
        const float ga = __builtin_amdgcn_rcpf(1.f + __expf(-ya));
        const float la = -ga * cdec[jt];
        const float a  = fminf(__expf(la), 1.0f - EPS5);
        const float mult = sqrtf(fmaxf(fmaf(-a, a, 1.0f), EPS5));
        aenc[jt] = (1.0f - a) * OMSCALE;
        nxv[jt]  = (float)xv[jt] * gx * mult;
        sla[jt] += fminf(la, LOG1MEPS);
      }
      f16x4 st = { (_Float16)aenc[0], (_Float16)nxv[0],
                   (_Float16)aenc[1], (_Float16)nxv[1] };
      *(f16x4*)&AU[obase + (size_t)row * D_] = st;
    }
  }
  // reduce log-a sums across quads (rows partitioned by quad) and emit CS
  #pragma unroll
  for (int jt = 0; jt < 2; ++jt) {
    sla[jt] += __shfl_xor(sla[jt], 16, 64);
    sla[jt] += __shfl_xor(sla[jt], 32, 64);
  }
  if (quad == 0) {
    const int csb = (b * NC_ + kc) * D_ + h * BW_ + jcp;
    *(float2*)&CS[csb] = make_float2(sla[0], sla[1]);
  }
}

// ---------------------------------------------------------------------------
// K2: in-place exclusive prefix over chunk log-sums (CS -> log q at starts).
// ---------------------------------------------------------------------------
__global__ __launch_bounds__(256) void k2_scan_logs(float* __restrict__ CS)
{
  const int idx = blockIdx.x * 256 + threadIdx.x;   // B_*D_ threads
  const int b = idx >> 10;
  const int d = idx & (D_ - 1);
  float lq = 0.f;
  #pragma unroll
  for (int kk = 0; kk < NC_; ++kk) {
    const int o = (b * NC_ + kk) * D_ + d;
    const float c = CS[o];
    CS[o] = lq;
    lq += c;
  }
}

// shared per-step scan decay. State: c = q_{t-1}, pp = p_{t-1}, aprev = a_{t-1}
__device__ __forceinline__ float scan_r(float c, float pp, float aprev) {
  return (c > EPS7) ? aprev
                    : ((pp > EPS7) ? (EPS7 * __builtin_amdgcn_rcpf(pp)) : 1.0f);
}

// ---------------------------------------------------------------------------
// K3a: per-chunk linear composition summary (A = prod r, B = local scan end).
// Thread owns 4 adjacent columns: f16x8 loads = 16 B/lane (coalescing sweet
// spot, 1/4 the VMEM issues of the f16x2 scheme), 4 independent chains for
// VALU ILP. 2-deep batch ping-pong (compile-time indices).
// ---------------------------------------------------------------------------
__global__ __launch_bounds__(256) void k3_summary(
    const f16x2* __restrict__ AU, const float* __restrict__ LQ,
    float* __restrict__ Ak, float* __restrict__ Bk)
{
  const int k = blockIdx.x & (NC_ - 1);
  const int b = blockIdx.x >> 5;
  const int d0 = threadIdx.x * 4;
  const size_t base = (size_t)(b * T_ + k * CT_) * D_ + d0;

  float c[4], pp[4], ap[4], hv[4], rp[4];
  if (k == 0) {
    #pragma unroll
    for (int ch = 0; ch < 4; ++ch) { c[ch] = 1.f; pp[ch] = 1.f; ap[ch] = 1.f; }
  } else {
    const float4 lq = *(const float4*)&LQ[(b * NC_ + k) * D_ + d0];
    const f16x8 ab = *(const f16x8*)&AU[base - D_];
    const float lqa[4] = {lq.x, lq.y, lq.z, lq.w};
    #pragma unroll
    for (int ch = 0; ch < 4; ++ch) {
      c[ch]  = __expf(lqa[ch]);
      ap[ch] = fmaf((float)ab[2 * ch], -INVOMS, 1.0f);
      pp[ch] = fmaxf(c[ch] / ap[ch], EPS7);
    }
  }
  #pragma unroll
  for (int ch = 0; ch < 4; ++ch) { hv[ch] = 0.f; rp[ch] = 1.f; }

  f16x8 buf[2][8];
  #pragma unroll
  for (int i = 0; i < 8; ++i)
    buf[0][i] = *(const f16x8*)&AU[base + (size_t)i * D_];

  #pragma unroll
  for (int tb = 0; tb < 16; ++tb) {
    const int cur = tb & 1, nxt = cur ^ 1;
    if (tb < 15) {
      const size_t o = base + (size_t)((tb + 1) * 8) * D_;
      #pragma unroll
      for (int i = 0; i < 8; ++i)
        buf[nxt][i] = *(const f16x8*)&AU[o + (size_t)i * D_];
    }
    #pragma unroll
    for (int i = 0; i < 8; ++i) {
      const f16x8 f = buf[cur][i];
      #pragma unroll
      for (int ch = 0; ch < 4; ++ch) {
        const float a = fmaf((float)f[2 * ch], -INVOMS, 1.0f);
        const float u = (float)f[2 * ch + 1] + EPS7;
        const float p = fmaxf(c[ch], EPS7);
        const float r = scan_r(c[ch], pp[ch], ap[ch]);
        hv[ch] = fmaf(r, hv[ch], u);
        rp[ch] *= r;
        c[ch] *= a; pp[ch] = p; ap[ch] = a;
      }
    }
  }
  const int o = (b * NC_ + k) * D_ + d0;
  *(float4*)&Ak[o] = (float4){rp[0], rp[1], rp[2], rp[3]};
  *(float4*)&Bk[o] = (float4){hv[0], hv[1], hv[2], hv[3]};
}

// ---------------------------------------------------------------------------
// K3b: chain chunk summaries -> h carry-in per chunk (in place: Ak -> Hc).
// ---------------------------------------------------------------------------
__global__ __launch_bounds__(256) void k3_carry(
    float* __restrict__ Ak, const float* __restrict__ Bk)
{
  const int idx = blockIdx.x * 256 + threadIdx.x;
  const int b = idx >> 10;
  const int d = idx & (D_ - 1);
  float Hv = 0.f;
  #pragma unroll
  for (int kk = 0; kk < NC_; ++kk) {
    const int o = (b * NC_ + kk) * D_ + d;
    const float Av = Ak[o];
    Ak[o] = Hv;
    Hv = fmaf(Av, Hv, Bk[o]);
  }
}

// ---------------------------------------------------------------------------
// K3c: seeded full scan; reads interleaved f16 AU, writes fp32 h to out.
// ---------------------------------------------------------------------------
__global__ __launch_bounds__(256) void k3_scan(
    const f16x2* __restrict__ AU, const float* __restrict__ LQ,
    const float* __restrict__ Hc, float* __restrict__ out)
{
  const int k = blockIdx.x & (NC_ - 1);
  const int b = blockIdx.x >> 5;
  const int d0 = threadIdx.x * 4;
  const size_t base = (size_t)(b * T_ + k * CT_) * D_ + d0;
  float* __restrict__ op = out + base;

  float c[4], pp[4], ap[4], hv[4];
  if (k == 0) {
    #pragma unroll
    for (int ch = 0; ch < 4; ++ch) { c[ch] = 1.f; pp[ch] = 1.f; ap[ch] = 1.f; }
  } else {
    const float4 lq = *(const float4*)&LQ[(b * NC_ + k) * D_ + d0];
    const f16x8 ab = *(const f16x8*)&AU[base - D_];
    const float lqa[4] = {lq.x, lq.y, lq.z, lq.w};
    #pragma unroll
    for (int ch = 0; ch < 4; ++ch) {
      c[ch]  = __expf(lqa[ch]);
      ap[ch] = fmaf((float)ab[2 * ch], -INVOMS, 1.0f);
      pp[ch] = fmaxf(c[ch] / ap[ch], EPS7);
    }
  }
  {
    const float4 hc = *(const float4*)&Hc[(b * NC_ + k) * D_ + d0];
    hv[0] = hc.x; hv[1] = hc.y; hv[2] = hc.z; hv[3] = hc.w;
  }

  f16x8 buf[2][8];
  #pragma unroll
  for (int i = 0; i < 8; ++i)
    buf[0][i] = *(const f16x8*)&AU[base + (size_t)i * D_];

  #pragma unroll
  for (int tb = 0; tb < 16; ++tb) {
    const int cur = tb & 1, nxt = cur ^ 1;
    if (tb < 15) {
      const size_t o = base + (size_t)((tb + 1) * 8) * D_;
      #pragma unroll
      for (int i = 0; i < 8; ++i)
        buf[nxt][i] = *(const f16x8*)&AU[o + (size_t)i * D_];
    }
    #pragma unroll
    for (int i = 0; i < 8; ++i) {
      const f16x8 f = buf[cur][i];
      #pragma unroll
      for (int ch = 0; ch < 4; ++ch) {
        const float a = fmaf((float)f[2 * ch], -INVOMS, 1.0f);
        const float u = (float)f[2 * ch + 1] + EPS7;
        const float p = fmaxf(c[ch], EPS7);
        const float r = scan_r(c[ch], pp[ch], ap[ch]);
        hv[ch] = fmaf(r, hv[ch], u);
        c[ch] *= a; pp[ch] = p; ap[ch] = a;
      }
      *(float4*)&op[(size_t)(tb * 8 + i) * D_] =
          (float4){hv[0], hv[1], hv[2], hv[3]};
    }
  }
}

extern "C" void kernel_launch(void* const* d_in, const int* in_sizes, int n_in,
                              void* d_out, int out_size, void* d_ws, size_t ws_size,
                              hipStream_t stream) {
  const float* x       = (const float*)d_in[0];
  const float* a_param = (const float*)d_in[1];
  const float* w_in    = (const float*)d_in[2];
  const float* b_in    = (const float*)d_in[3];
  const float* w_a     = (const float*)d_in[4];
  const float* b_a     = (const float*)d_in[5];
  float* out = (float*)d_out;

  // Workspace layout: byte-identical to the round-2 run that passed (131 MiB).
  char* ws = (char*)d_ws;
  f16x2* AU = (f16x2*)ws;                                      // 128 MiB
  float* CS = (float*)(ws + (size_t)B_ * T_ * D_ * 4);         // 1 MiB (-> LQ)
  float* Ak = CS + B_ * NC_ * D_;                              // 1 MiB (-> Hc)
  float* Bk = Ak + B_ * NC_ * D_;                              // 1 MiB

  k1_gates<<<B_ * H_ * NC_, 256, 0, stream>>>(x, a_param, w_in, b_in, w_a, b_a,
                                              AU, CS);
  k2_scan_logs<<<(B_ * D_) / 256, 256, 0, stream>>>(CS);
  k3_summary<<<B_ * NC_, 256, 0, stream>>>(AU, CS, Ak, Bk);
  k3_carry<<<(B_ * D_) / 256, 256, 0, stream>>>(Ak, Bk);
  k3_scan<<<B_ * NC_, 256, 0, stream>>>(AU, CS, Ak, out);
}

// Round 6
// 367.615 us; speedup vs baseline: 1.3549x; 1.3549x over previous
//
#include <hip/hip_runtime.h>

#define B_ 8
#define T_ 4096
#define D_ 1024
#define H_ 8
#define BW_ 128
#define NC_ 32           // scan chunks (128 rows each)
#define CT_ 128
#define EPS7 1e-7f
#define EPS5 1e-5f
#define LOG1MEPS -1.0000186e-05f   // log(1 - 1e-5)
#define OMSCALE 256.0f
#define INVOMS 0.00390625f         // 1/256

typedef _Float16 f16x8 __attribute__((ext_vector_type(8)));
typedef _Float16 f16x4 __attribute__((ext_vector_type(4)));
typedef _Float16 f16x2 __attribute__((ext_vector_type(2)));
typedef float f32x4 __attribute__((ext_vector_type(4)));

// ---------------------------------------------------------------------------
// K1: block (b, head, 128-row tile). Gate matmuls on MFMA f16 (16x16x32).
// Column permutation: MFMA logical col l15 -> actual col wave*32 + 2*l15 + jt,
// so each thread's two output columns are ADJACENT. Output interleaved
// AU[t][d] = (a_enc, nx) f16 pairs written as f16x4 (8 B/lane coalesced).
// a_enc = (1-a)*256 (raw a would round to 1.0 in f16). [round-5, passed]
// ---------------------------------------------------------------------------
__global__ __launch_bounds__(256) void k1_gates(
    const float* __restrict__ x, const float* __restrict__ a_param,
    const float* __restrict__ w_in, const float* __restrict__ b_in,
    const float* __restrict__ w_a, const float* __restrict__ b_a,
    f16x2* __restrict__ AU, float* __restrict__ CS)
{
  const int bid  = blockIdx.x;
  const int kc   = bid & (NC_ - 1);
  const int h    = (bid >> 5) & (H_ - 1);
  const int b    = bid >> 8;
  const int tid  = threadIdx.x;
  const int wave = tid >> 6;
  const int lane = tid & 63;
  const int quad = lane >> 4;
  const int l15  = lane & 15;

  __shared__ _Float16 xs[128 * 136];   // 128 rows x 128 K f16, pad 8/row

  const float* xg = x + (size_t)(b * T_ + kc * CT_) * D_ + h * BW_;
  const int jcp = wave * 32 + 2 * l15;   // even pair-column within head

  // --- B fragments (weights) from global, permuted col ---
  f16x8 bf[2][2][4];   // [gate][jtile][kstep]
  #pragma unroll
  for (int g = 0; g < 2; ++g) {
    const float* wptr = (g ? w_a : w_in) + h * BW_ * BW_;
    #pragma unroll
    for (int jt = 0; jt < 2; ++jt) {
      #pragma unroll
      for (int k = 0; k < 4; ++k) {
        const float* wp = wptr + (k * 32 + quad * 8) * BW_ + jcp + jt;
        f16x8 f;
        #pragma unroll
        for (int i = 0; i < 8; ++i) f[i] = (_Float16)wp[i * BW_];
        bf[g][jt][k] = f;
      }
    }
  }
  // per-lane j constants (actual columns jcp+jt)
  float bI[2], bA[2], cdec[2];
  #pragma unroll
  for (int jt = 0; jt < 2; ++jt) {
    const int j = h * BW_ + jcp + jt;
    bI[jt] = b_in[j];
    bA[jt] = b_a[j];
    const float ap = a_param[j];
    cdec[jt] = ((ap > 20.f) ? ap : log1pf(__expf(ap))) + 0.001f;
  }

  // --- stage x -> LDS f16; per half-wave: one row, 512 B contiguous ---
  {
    const int rr = tid >> 5;          // 0..7
    const int cc = (tid & 31) * 4;    // 0..124
    #pragma unroll
    for (int i = 0; i < 16; ++i) {
      const int row = i * 8 + rr;
      const float4 v = *(const float4*)(xg + row * D_ + cc);
      f16x4 hv = { (_Float16)v.x, (_Float16)v.y, (_Float16)v.z, (_Float16)v.w };
      *(f16x4*)(xs + row * 136 + cc) = hv;
    }
  }
  __syncthreads();

  // --- MFMA main loop: 8 m-tiles x 4 k-steps x 2 gates x 2 j-tiles ---
  f32x4 acc[2][2][8];
  #pragma unroll
  for (int g = 0; g < 2; ++g)
    #pragma unroll
    for (int jt = 0; jt < 2; ++jt)
      #pragma unroll
      for (int m = 0; m < 8; ++m)
        acc[g][jt][m] = (f32x4){0.f, 0.f, 0.f, 0.f};

  #pragma unroll
  for (int m = 0; m < 8; ++m) {
    f16x8 af[4];
    #pragma unroll
    for (int k = 0; k < 4; ++k)
      af[k] = *(const f16x8*)(xs + (m * 16 + l15) * 136 + k * 32 + quad * 8);
    #pragma unroll
    for (int k = 0; k < 4; ++k)
      #pragma unroll
      for (int g = 0; g < 2; ++g)
        #pragma unroll
        for (int jt = 0; jt < 2; ++jt)
          acc[g][jt][m] = __builtin_amdgcn_mfma_f32_16x16x32_f16(
              af[k], bf[g][jt][k], acc[g][jt][m], 0, 0, 0);
  }

  // --- epilogue: D layout col(logical)=l15, row = m*16 + quad*4 + reg ---
  float sla[2] = {0.f, 0.f};
  const size_t obase = (size_t)(b * T_ + kc * CT_) * D_ + h * BW_ + jcp;
  #pragma unroll
  for (int m = 0; m < 8; ++m) {
    #pragma unroll
    for (int r = 0; r < 4; ++r) {
      const int row = m * 16 + quad * 4 + r;
      const f16x2 xv = *(const f16x2*)(xs + row * 136 + jcp);
      float aenc[2], nxv[2];
      #pragma unroll
      for (int jt = 0; jt < 2; ++jt) {
        const float yi = acc[0][jt][m][r] + bI[jt];
        const float ya = acc[1][jt][m][r] + bA[jt];
        const float gx = __builtin_amdgcn_rcpf(1.f + __expf(-yi));
        const float ga = __builtin_amdgcn_rcpf(1.f + __expf(-ya));
        const float la = -ga * cdec[jt];
        const float a  = fminf(__expf(la), 1.0f - EPS5);
        const float mult = sqrtf(fmaxf(fmaf(-a, a, 1.0f), EPS5));
        aenc[jt] = (1.0f - a) * OMSCALE;
        nxv[jt]  = (float)xv[jt] * gx * mult;
        sla[jt] += fminf(la, LOG1MEPS);
      }
      f16x4 st = { (_Float16)aenc[0], (_Float16)nxv[0],
                   (_Float16)aenc[1], (_Float16)nxv[1] };
      *(f16x4*)&AU[obase + (size_t)row * D_] = st;
    }
  }
  // reduce log-a sums across quads (rows partitioned by quad) and emit CS
  #pragma unroll
  for (int jt = 0; jt < 2; ++jt) {
    sla[jt] += __shfl_xor(sla[jt], 16, 64);
    sla[jt] += __shfl_xor(sla[jt], 32, 64);
  }
  if (quad == 0) {
    const int csb = (b * NC_ + kc) * D_ + h * BW_ + jcp;
    *(float2*)&CS[csb] = make_float2(sla[0], sla[1]);
  }
}

// ---------------------------------------------------------------------------
// K2: in-place exclusive prefix over chunk log-sums (CS -> log q at starts).
// ---------------------------------------------------------------------------
__global__ __launch_bounds__(256) void k2_scan_logs(float* __restrict__ CS)
{
  const int idx = blockIdx.x * 256 + threadIdx.x;   // B_*D_ threads
  const int b = idx >> 10;
  const int d = idx & (D_ - 1);
  float lq = 0.f;
  #pragma unroll
  for (int kk = 0; kk < NC_; ++kk) {
    const int o = (b * NC_ + kk) * D_ + d;
    const float c = CS[o];
    CS[o] = lq;
    lq += c;
  }
}

// shared per-step scan decay. State: c = q_{t-1}, pp = p_{t-1}, aprev = a_{t-1}
__device__ __forceinline__ float scan_r(float c, float pp, float aprev) {
  return (c > EPS7) ? aprev
                    : ((pp > EPS7) ? (EPS7 * __builtin_amdgcn_rcpf(pp)) : 1.0f);
}

// Per-step scan body for 2 channels packed in one f16x4 (a0,u0,a1,u1).
#define SCAN_STEP(f)                                                \
  {                                                                 \
    const float a0 = fmaf((float)(f)[0], -INVOMS, 1.0f);            \
    const float u0 = (float)(f)[1] + EPS7;                          \
    const float a1 = fmaf((float)(f)[2], -INVOMS, 1.0f);            \
    const float u1 = (float)(f)[3] + EPS7;                          \
    const float p0 = fmaxf(c0, EPS7);                               \
    const float r0 = scan_r(c0, pp0, ap0);                          \
    hv0 = fmaf(r0, hv0, u0);                                        \
    const float p1 = fmaxf(c1, EPS7);                               \
    const float r1 = scan_r(c1, pp1, ap1);                          \
    hv1 = fmaf(r1, hv1, u1);                                        \
    rp0 *= r0; rp1 *= r1;                                           \
    c0 *= a0; pp0 = p0; ap0 = a0;                                   \
    c1 *= a1; pp1 = p1; ap1 = a1;                                   \
  }

// ---------------------------------------------------------------------------
// K3a: per-chunk linear composition summary (A = prod r, B = local scan end).
// Spill fix vs round 5: named bufA/bufB (all compile-time indices) + a
// RUNTIME outer loop (#pragma unroll 1) so the compiler cannot hoist more
// than one batch of loads (round 5's full unroll wanted ~512 VGPRs -> 124 MB
// of scratch spill writes, VGPR=256). 2 channels/thread, 2 blocks/chunk ->
// 512 blocks = 2 blocks/CU for TLP (was 1).
// ---------------------------------------------------------------------------
__global__ __launch_bounds__(256) void k3_summary(
    const f16x2* __restrict__ AU, const float* __restrict__ LQ,
    float* __restrict__ Ak, float* __restrict__ Bk)
{
  const int half = blockIdx.x & 1;
  const int k = (blockIdx.x >> 1) & (NC_ - 1);
  const int b = blockIdx.x >> 6;
  const int d0 = half * 512 + threadIdx.x * 2;
  const size_t base = (size_t)(b * T_ + k * CT_) * D_ + d0;

  float c0, pp0, ap0, c1, pp1, ap1;
  if (k == 0) { c0 = c1 = 1.f; pp0 = pp1 = 1.f; ap0 = ap1 = 1.f; }
  else {
    const float2 lq = *(const float2*)&LQ[(b * NC_ + k) * D_ + d0];
    c0 = __expf(lq.x); c1 = __expf(lq.y);
    const f16x4 ab = *(const f16x4*)&AU[base - D_];
    ap0 = fmaf((float)ab[0], -INVOMS, 1.0f);
    ap1 = fmaf((float)ab[2], -INVOMS, 1.0f);
    pp0 = fmaxf(c0 / ap0, EPS7);
    pp1 = fmaxf(c1 / ap1, EPS7);
  }
  float hv0 = 0.f, hv1 = 0.f, rp0 = 1.f, rp1 = 1.f;

  f16x4 bufA[8], bufB[8];
  #pragma unroll
  for (int i = 0; i < 8; ++i)
    bufA[i] = *(const f16x4*)&AU[base + (size_t)i * D_];

  #pragma unroll 1
  for (int tb = 0; tb < 16; tb += 2) {
    {
      const size_t o = base + (size_t)((tb + 1) * 8) * D_;
      #pragma unroll
      for (int i = 0; i < 8; ++i)
        bufB[i] = *(const f16x4*)&AU[o + (size_t)i * D_];
    }
    #pragma unroll
    for (int i = 0; i < 8; ++i) SCAN_STEP(bufA[i]);
    if (tb < 14) {
      const size_t o = base + (size_t)((tb + 2) * 8) * D_;
      #pragma unroll
      for (int i = 0; i < 8; ++i)
        bufA[i] = *(const f16x4*)&AU[o + (size_t)i * D_];
    }
    #pragma unroll
    for (int i = 0; i < 8; ++i) SCAN_STEP(bufB[i]);
  }
  const int o = (b * NC_ + k) * D_ + d0;
  *(float2*)&Ak[o] = make_float2(rp0, rp1);
  *(float2*)&Bk[o] = make_float2(hv0, hv1);
}

// ---------------------------------------------------------------------------
// K3b: chain chunk summaries -> h carry-in per chunk (in place: Ak -> Hc).
// ---------------------------------------------------------------------------
__global__ __launch_bounds__(256) void k3_carry(
    float* __restrict__ Ak, const float* __restrict__ Bk)
{
  const int idx = blockIdx.x * 256 + threadIdx.x;
  const int b = idx >> 10;
  const int d = idx & (D_ - 1);
  float Hv = 0.f;
  #pragma unroll
  for (int kk = 0; kk < NC_; ++kk) {
    const int o = (b * NC_ + kk) * D_ + d;
    const float Av = Ak[o];
    Ak[o] = Hv;
    Hv = fmaf(Av, Hv, Bk[o]);
  }
}

// Scan step + fp32 h store for k3_scan (2 channels).
#define SCAN_STEP_ST(f, t)                                          \
  {                                                                 \
    const float a0 = fmaf((float)(f)[0], -INVOMS, 1.0f);            \
    const float u0 = (float)(f)[1] + EPS7;                          \
    const float a1 = fmaf((float)(f)[2], -INVOMS, 1.0f);            \
    const float u1 = (float)(f)[3] + EPS7;                          \
    const float p0 = fmaxf(c0, EPS7);                               \
    const float r0 = scan_r(c0, pp0, ap0);                          \
    hv0 = fmaf(r0, hv0, u0);                                        \
    const float p1 = fmaxf(c1, EPS7);                               \
    const float r1 = scan_r(c1, pp1, ap1);                          \
    hv1 = fmaf(r1, hv1, u1);                                        \
    *(float2*)&op[(size_t)(t) * D_] = make_float2(hv0, hv1);        \
    c0 *= a0; pp0 = p0; ap0 = a0;                                   \
    c1 *= a1; pp1 = p1; ap1 = a1;                                   \
  }

// ---------------------------------------------------------------------------
// K3c: seeded full scan; reads interleaved f16 AU, writes fp32 h to out.
// Same spill-safe ping-pong structure as K3a.
// ---------------------------------------------------------------------------
__global__ __launch_bounds__(256) void k3_scan(
    const f16x2* __restrict__ AU, const float* __restrict__ LQ,
    const float* __restrict__ Hc, float* __restrict__ out)
{
  const int half = blockIdx.x & 1;
  const int k = (blockIdx.x >> 1) & (NC_ - 1);
  const int b = blockIdx.x >> 6;
  const int d0 = half * 512 + threadIdx.x * 2;
  const size_t base = (size_t)(b * T_ + k * CT_) * D_ + d0;
  float* __restrict__ op = out + base;

  float c0, pp0, ap0, c1, pp1, ap1;
  if (k == 0) { c0 = c1 = 1.f; pp0 = pp1 = 1.f; ap0 = ap1 = 1.f; }
  else {
    const float2 lq = *(const float2*)&LQ[(b * NC_ + k) * D_ + d0];
    c0 = __expf(lq.x); c1 = __expf(lq.y);
    const f16x4 ab = *(const f16x4*)&AU[base - D_];
    ap0 = fmaf((float)ab[0], -INVOMS, 1.0f);
    ap1 = fmaf((float)ab[2], -INVOMS, 1.0f);
    pp0 = fmaxf(c0 / ap0, EPS7);
    pp1 = fmaxf(c1 / ap1, EPS7);
  }
  float hv0, hv1;
  {
    const float2 hc = *(const float2*)&Hc[(b * NC_ + k) * D_ + d0];
    hv0 = hc.x; hv1 = hc.y;
  }

  f16x4 bufA[8], bufB[8];
  #pragma unroll
  for (int i = 0; i < 8; ++i)
    bufA[i] = *(const f16x4*)&AU[base + (size_t)i * D_];

  #pragma unroll 1
  for (int tb = 0; tb < 16; tb += 2) {
    {
      const size_t o = base + (size_t)((tb + 1) * 8) * D_;
      #pragma unroll
      for (int i = 0; i < 8; ++i)
        bufB[i] = *(const f16x4*)&AU[o + (size_t)i * D_];
    }
    #pragma unroll
    for (int i = 0; i < 8; ++i) SCAN_STEP_ST(bufA[i], tb * 8 + i);
    if (tb < 14) {
      const size_t o = base + (size_t)((tb + 2) * 8) * D_;
      #pragma unroll
      for (int i = 0; i < 8; ++i)
        bufA[i] = *(const f16x4*)&AU[o + (size_t)i * D_];
    }
    #pragma unroll
    for (int i = 0; i < 8; ++i) SCAN_STEP_ST(bufB[i], (tb + 1) * 8 + i);
  }
}

extern "C" void kernel_launch(void* const* d_in, const int* in_sizes, int n_in,
                              void* d_out, int out_size, void* d_ws, size_t ws_size,
                              hipStream_t stream) {
  const float* x       = (const float*)d_in[0];
  const float* a_param = (const float*)d_in[1];
  const float* w_in    = (const float*)d_in[2];
  const float* b_in    = (const float*)d_in[3];
  const float* w_a     = (const float*)d_in[4];
  const float* b_a     = (const float*)d_in[5];
  float* out = (float*)d_out;

  // Workspace layout: byte-identical to the rounds-2/5 runs that passed.
  char* ws = (char*)d_ws;
  f16x2* AU = (f16x2*)ws;                                      // 128 MiB
  float* CS = (float*)(ws + (size_t)B_ * T_ * D_ * 4);         // 1 MiB (-> LQ)
  float* Ak = CS + B_ * NC_ * D_;                              // 1 MiB (-> Hc)
  float* Bk = Ak + B_ * NC_ * D_;                              // 1 MiB

  k1_gates<<<B_ * H_ * NC_, 256, 0, stream>>>(x, a_param, w_in, b_in, w_a, b_a,
                                              AU, CS);
  k2_scan_logs<<<(B_ * D_) / 256, 256, 0, stream>>>(CS);
  k3_summary<<<B_ * NC_ * 2, 256, 0, stream>>>(AU, CS, Ak, Bk);
  k3_carry<<<(B_ * D_) / 256, 256, 0, stream>>>(Ak, Bk);
  k3_scan<<<B_ * NC_ * 2, 256, 0, stream>>>(AU, CS, Ak, out);
}